// Round 2
// baseline (146.951 us; speedup 1.0000x reference)
//
#include <hip/hip_runtime.h>

// B=8, C=128, H=W=256, P=2, R=2, WP=3, HID=8.  Output xp: (B,C,260,260) fp32.
// Kernel 1 (border): one block per (b,c) slice; simulate the 4-stage border
//   program {top0,bot0}->{left0,right0}->{top1,bot1}->{left1,right1} in LDS,
//   weights fetched via wave-uniform scalar loads (SGPR operands on v_fma).
//   Writes the 2-wide frame to d_out.
// Kernel 2 (assemble): writes every interior row (xp rows 2..257) as 65
//   aligned float4s, sourcing cols {0,1,258,259} from the frame in d_out and
//   cols 2..257 from x. Full-row aligned writes: no partial-line RMW.

__device__ __forceinline__ int bmap(int r) { return r < 4 ? r : r - 251; }

template <int S>
__device__ __forceinline__ float mlp6(const float* __restrict__ v,
                                      const float* __restrict__ w1,
                                      const float* __restrict__ b1,
                                      const float* __restrict__ w2,
                                      const float* __restrict__ b2,
                                      const float* __restrict__ w3,
                                      const float* __restrict__ b3)
{
    const float* __restrict__ W1 = w1 + S * 48;  // [8][6]
    const float* __restrict__ B1 = b1 + S * 8;
    const float* __restrict__ W2 = w2 + S * 64;  // [8][8]
    const float* __restrict__ B2 = b2 + S * 8;
    const float* __restrict__ W3 = w3 + S * 8;
    const float  b3s = b3[S];

    float h1[8];
#pragma unroll
    for (int h = 0; h < 8; ++h) {
        float a = B1[h];
#pragma unroll
        for (int q = 0; q < 6; ++q) a = fmaf(v[q], W1[h * 6 + q], a);
        h1[h] = fmaxf(a, 0.f);
    }
    float h2[8];
#pragma unroll
    for (int g = 0; g < 8; ++g) {
        float a = B2[g];
#pragma unroll
        for (int h = 0; h < 8; ++h) a = fmaf(h1[h], W2[g * 8 + h], a);
        h2[g] = fmaxf(a, 0.f);
    }
    float o = b3s;
#pragma unroll
    for (int g = 0; g < 8; ++g) o = fmaf(h2[g], W3[g], o);
    return fmaxf(o, 0.f);
}

// horizontal pass (S=0 top, S=1 bottom) for iteration `it`
template <int S>
__device__ __forceinline__ void hstage(int it, int tid,
                                       float (*rowS)[260], float (*colS)[260],
                                       const float* __restrict__ w1, const float* __restrict__ b1,
                                       const float* __restrict__ w2, const float* __restrict__ b2,
                                       const float* __restrict__ w3, const float* __restrict__ b3)
{
    int rin0, rin1, rout;
    if (S == 0) { rin0 = 2 - it;   rin1 = 3 - it;   rout = 1 - it;   }
    else        { rin0 = 255 + it; rin1 = 256 + it; rout = 258 + it; }
    const int a0 = bmap(rin0), a1 = bmap(rin1), ao = bmap(rout);
    for (int j0 = tid; j0 < 258; j0 += 256) {
        int j = j0 + 1;
        float v[6];
        v[0] = rowS[a0][j - 1]; v[1] = rowS[a0][j]; v[2] = rowS[a0][j + 1];
        v[3] = rowS[a1][j - 1]; v[4] = rowS[a1][j]; v[5] = rowS[a1][j + 1];
        float o = mlp6<S>(v, w1, b1, w2, b2, w3, b3);
        rowS[ao][j] = o;
        if (j < 4 || j >= 255) colS[bmap(j)][rout] = o;  // keep col views consistent
    }
}

// vertical pass (S=2 left, S=3 right)
template <int S>
__device__ __forceinline__ void vstage(int it, int tid,
                                       float (*rowS)[260], float (*colS)[260],
                                       const float* __restrict__ w1, const float* __restrict__ b1,
                                       const float* __restrict__ w2, const float* __restrict__ b2,
                                       const float* __restrict__ w3, const float* __restrict__ b3)
{
    int cin0, cin1, cout;
    if (S == 2) { cin0 = 2 - it;   cin1 = 3 - it;   cout = 1 - it;   }
    else        { cin0 = 255 + it; cin1 = 256 + it; cout = 258 + it; }
    const int a0 = bmap(cin0), a1 = bmap(cin1), ao = bmap(cout);
    for (int r0 = tid; r0 < 258; r0 += 256) {
        int r = r0 + 1;
        float v[6];
        v[0] = colS[a0][r - 1]; v[1] = colS[a0][r]; v[2] = colS[a0][r + 1];
        v[3] = colS[a1][r - 1]; v[4] = colS[a1][r]; v[5] = colS[a1][r + 1];
        float o = mlp6<S>(v, w1, b1, w2, b2, w3, b3);
        colS[ao][r] = o;
        if (r < 4 || r >= 255) rowS[bmap(r)][cout] = o;  // keep row views consistent
    }
}

__global__ __launch_bounds__(256) void border_kernel(
    const float* __restrict__ x,
    const float* __restrict__ w1, const float* __restrict__ b1,
    const float* __restrict__ w2, const float* __restrict__ b2,
    const float* __restrict__ w3, const float* __restrict__ b3,
    float* __restrict__ out)
{
    const int tid = threadIdx.x;
    const int bc  = blockIdx.x;                     // b*128 + c
    const float* xs = x + (size_t)bc * 65536;
    float*       os = out + (size_t)bc * 67600;

    // tracked xp rows/cols {0,1,2,3,255,256,257,258,259}
    __shared__ float rowS[9][260];
    __shared__ float colS[9][260];

    for (int idx = tid; idx < 9 * 260; idx += 256) {
        (&rowS[0][0])[idx] = 0.f;
        (&colS[0][0])[idx] = 0.f;
    }
    __syncthreads();

    // xp rows 2,3 = x rows 0,1 ; xp rows 255,256,257 = x rows 253,254,255
    for (int which = 0; which < 5; ++which) {
        int xr = which < 2 ? which : 251 + which;   // 0,1,253,254,255
        rowS[2 + which][2 + tid] = xs[xr * 256 + tid];
        colS[2 + which][2 + tid] = xs[tid * 256 + xr];
    }
    __syncthreads();

    for (int it = 0; it < 2; ++it) {
        hstage<0>(it, tid, rowS, colS, w1, b1, w2, b2, w3, b3);
        hstage<1>(it, tid, rowS, colS, w1, b1, w2, b2, w3, b3);
        __syncthreads();
        vstage<2>(it, tid, rowS, colS, w1, b1, w2, b2, w3, b3);
        vstage<3>(it, tid, rowS, colS, w1, b1, w2, b2, w3, b3);
        __syncthreads();
    }

    // final frame: rows 0,1,258,259 full width
    for (int idx = tid; idx < 4 * 260; idx += 256) {
        int w = idx / 260, cc = idx % 260;
        int rr = w < 2 ? w : 256 + w;               // 0,1,258,259
        os[(size_t)rr * 260 + cc] = rowS[bmap(rr)][cc];
    }
    // cols 0,1,258,259 for rows 2..257
    for (int idx = tid; idx < 4 * 256; idx += 256) {
        int w = idx >> 8, r = (idx & 255) + 2;
        int cc = w < 2 ? w : 256 + w;
        os[(size_t)r * 260 + cc] = colS[bmap(cc)][r];
    }
}

// Interior rows as full aligned float4 rows. grid (65, 1024), block 256:
// idx in [0,16640) -> x row r = idx/65, float4 slot k = idx%65.
__global__ __launch_bounds__(256) void assemble_kernel(const float* __restrict__ x,
                                                       float* out)
{
    const int bc = blockIdx.y;
    const float* xrowbase = x + (size_t)bc * 65536;
    float*       os       = out + (size_t)bc * 67600;

    int idx = blockIdx.x * 256 + threadIdx.x;      // 0..16639
    int r   = idx / 65;                            // 0..255
    int k   = idx - r * 65;                        // 0..64

    float*       orow = os + (size_t)(r + 2) * 260;
    const float* xrow = xrowbase + (size_t)r * 256;

    float4 val;
    if (k == 0) {
        float2 b = *(const float2*)(orow);         // frame cols 0,1 (border_kernel)
        float2 a = *(const float2*)(xrow);
        val = make_float4(b.x, b.y, a.x, a.y);
    } else if (k == 64) {
        float2 a = *(const float2*)(xrow + 254);
        float2 b = *(const float2*)(orow + 258);   // frame cols 258,259
        val = make_float4(a.x, a.y, b.x, b.y);
    } else {
        float2 a = *(const float2*)(xrow + 4 * k - 2);
        float2 c = *(const float2*)(xrow + 4 * k);
        val = make_float4(a.x, a.y, c.x, c.y);
    }
    *(float4*)(orow + 4 * k) = val;                // 16B-aligned full-row store
}

extern "C" void kernel_launch(void* const* d_in, const int* in_sizes, int n_in,
                              void* d_out, int out_size, void* d_ws, size_t ws_size,
                              hipStream_t stream)
{
    const float* x  = (const float*)d_in[0];
    const float* w1 = (const float*)d_in[1];
    const float* b1 = (const float*)d_in[2];
    const float* w2 = (const float*)d_in[3];
    const float* b2 = (const float*)d_in[4];
    const float* w3 = (const float*)d_in[5];
    const float* b3 = (const float*)d_in[6];
    float* out = (float*)d_out;

    border_kernel<<<1024, 256, 0, stream>>>(x, w1, b1, w2, b2, w3, b3, out);
    assemble_kernel<<<dim3(65, 1024), 256, 0, stream>>>(x, out);
}

// Round 3
// 140.106 us; speedup vs baseline: 1.0489x; 1.0489x over previous
//
#include <hip/hip_runtime.h>

// B=8, C=128, H=W=256, P=2, R=2, WP=3, HID=8. Output xp: (B,C,260,260) fp32.
// Single fused kernel: one block per (b,c) slice.
//   Phase A: load the 5 tracked rows + 5 tracked cols of x into LDS.
//   Phase B: 4-stage border program {top,bot}->{left,right} x2 in LDS,
//            weights via wave-uniform scalar (SGPR) loads.
//   Phase C: write frame rows 0,1,258,259 from LDS.
//   Phase D: stream interior rows (xp 2..257) as 65 aligned float4 each;
//            frame cols come straight from LDS (no d_out reads).
// Bulk traffic uses nontemporal loads/stores to avoid L2 thrash/allocate.

typedef float f32x4 __attribute__((ext_vector_type(4)));
typedef float f32x2 __attribute__((ext_vector_type(2)));

__device__ __forceinline__ int bmap(int r) { return r < 4 ? r : r - 251; }

template <int S>
__device__ __forceinline__ float mlp6(const float* v,
                                      const float* __restrict__ w1, const float* __restrict__ b1,
                                      const float* __restrict__ w2, const float* __restrict__ b2,
                                      const float* __restrict__ w3, const float* __restrict__ b3)
{
    const float* __restrict__ W1 = w1 + S * 48;  // [8][6]
    const float* __restrict__ B1 = b1 + S * 8;
    const float* __restrict__ W2 = w2 + S * 64;  // [8][8]
    const float* __restrict__ B2 = b2 + S * 8;
    const float* __restrict__ W3 = w3 + S * 8;
    const float  b3s = b3[S];

    float h1[8];
#pragma unroll
    for (int h = 0; h < 8; ++h) {
        float a = B1[h];
#pragma unroll
        for (int q = 0; q < 6; ++q) a = fmaf(v[q], W1[h * 6 + q], a);
        h1[h] = fmaxf(a, 0.f);
    }
    float h2[8];
#pragma unroll
    for (int g = 0; g < 8; ++g) {
        float a = B2[g];
#pragma unroll
        for (int h = 0; h < 8; ++h) a = fmaf(h1[h], W2[g * 8 + h], a);
        h2[g] = fmaxf(a, 0.f);
    }
    float o = b3s;
#pragma unroll
    for (int g = 0; g < 8; ++g) o = fmaf(h2[g], W3[g], o);
    return fmaxf(o, 0.f);
}

template <int S>
__device__ __forceinline__ void hstage(int it, int tid,
                                       float (*rowS)[260], float (*colS)[260],
                                       const float* __restrict__ w1, const float* __restrict__ b1,
                                       const float* __restrict__ w2, const float* __restrict__ b2,
                                       const float* __restrict__ w3, const float* __restrict__ b3)
{
    int rin0, rin1, rout;
    if (S == 0) { rin0 = 2 - it;   rin1 = 3 - it;   rout = 1 - it;   }
    else        { rin0 = 255 + it; rin1 = 256 + it; rout = 258 + it; }
    const int a0 = bmap(rin0), a1 = bmap(rin1), ao = bmap(rout);
    for (int j0 = tid; j0 < 258; j0 += 512) {
        int j = j0 + 1;
        float v[6];
        v[0] = rowS[a0][j - 1]; v[1] = rowS[a0][j]; v[2] = rowS[a0][j + 1];
        v[3] = rowS[a1][j - 1]; v[4] = rowS[a1][j]; v[5] = rowS[a1][j + 1];
        float o = mlp6<S>(v, w1, b1, w2, b2, w3, b3);
        rowS[ao][j] = o;
        if (j < 4 || j >= 255) colS[bmap(j)][rout] = o;  // keep col views consistent
    }
}

template <int S>
__device__ __forceinline__ void vstage(int it, int tid,
                                       float (*rowS)[260], float (*colS)[260],
                                       const float* __restrict__ w1, const float* __restrict__ b1,
                                       const float* __restrict__ w2, const float* __restrict__ b2,
                                       const float* __restrict__ w3, const float* __restrict__ b3)
{
    int cin0, cin1, cout;
    if (S == 2) { cin0 = 2 - it;   cin1 = 3 - it;   cout = 1 - it;   }
    else        { cin0 = 255 + it; cin1 = 256 + it; cout = 258 + it; }
    const int a0 = bmap(cin0), a1 = bmap(cin1), ao = bmap(cout);
    for (int r0 = tid; r0 < 258; r0 += 512) {
        int r = r0 + 1;
        float v[6];
        v[0] = colS[a0][r - 1]; v[1] = colS[a0][r]; v[2] = colS[a0][r + 1];
        v[3] = colS[a1][r - 1]; v[4] = colS[a1][r]; v[5] = colS[a1][r + 1];
        float o = mlp6<S>(v, w1, b1, w2, b2, w3, b3);
        colS[ao][r] = o;
        if (r < 4 || r >= 255) rowS[bmap(r)][cout] = o;  // keep row views consistent
    }
}

__global__ __launch_bounds__(512, 8) void fused_kernel(
    const float* __restrict__ x,
    const float* __restrict__ w1, const float* __restrict__ b1,
    const float* __restrict__ w2, const float* __restrict__ b2,
    const float* __restrict__ w3, const float* __restrict__ b3,
    float* __restrict__ out)
{
    const int tid = threadIdx.x;
    const int bc  = blockIdx.x;                     // b*128 + c
    const float* xs = x + (size_t)bc * 65536;
    float*       os = out + (size_t)bc * 67600;

    // tracked xp rows/cols {0,1,2,3,255,256,257,258,259} -> index 0..8
    __shared__ float rowS[9][260];
    __shared__ float colS[9][260];

    for (int idx = tid; idx < 9 * 260; idx += 512) {
        (&rowS[0][0])[idx] = 0.f;
        (&colS[0][0])[idx] = 0.f;
    }
    __syncthreads();

    // xp rows 2,3 = x rows 0,1 ; xp rows 255,256,257 = x rows 253,254,255
    for (int idx = tid; idx < 5 * 256; idx += 512) {
        int which = idx >> 8, t = idx & 255;
        int xr = which < 2 ? which : 251 + which;   // 0,1,253,254,255
        rowS[2 + which][2 + t] = xs[xr * 256 + t];
    }
    for (int idx = tid; idx < 5 * 256; idx += 512) {
        int which = idx >> 8, t = idx & 255;
        int xr = which < 2 ? which : 251 + which;
        colS[2 + which][2 + t] = xs[t * 256 + xr];
    }
    __syncthreads();

    for (int it = 0; it < 2; ++it) {
        hstage<0>(it, tid, rowS, colS, w1, b1, w2, b2, w3, b3);
        hstage<1>(it, tid, rowS, colS, w1, b1, w2, b2, w3, b3);
        __syncthreads();
        vstage<2>(it, tid, rowS, colS, w1, b1, w2, b2, w3, b3);
        vstage<3>(it, tid, rowS, colS, w1, b1, w2, b2, w3, b3);
        __syncthreads();
    }

    // Phase C: frame rows 0,1,258,259 full width (corners are LDS zeros)
    for (int idx = tid; idx < 4 * 260; idx += 512) {
        int w = idx / 260, cc = idx % 260;
        int rr = w < 2 ? w : 256 + w;               // 0,1,258,259
        __builtin_nontemporal_store(rowS[bmap(rr)][cc], &os[(size_t)rr * 260 + cc]);
    }

    // Phase D: interior rows xp 2..257, 65 aligned float4 per row.
    //   k==0  -> xp cols 0..3   = colS[0,1,2,3][rp]  (frame + x cols 0,1)
    //   k==64 -> xp cols 256..259 = colS[5,6,7,8][rp] (x cols 254,255 + frame)
    //   else  -> x[r][4k-2 .. 4k+1]
    for (int idx = tid; idx < 256 * 65; idx += 512) {
        int r = idx / 65;                           // x row, xp row r+2
        int k = idx - r * 65;
        int rp = r + 2;
        float* orow = os + (size_t)rp * 260;
        const float* xrow = xs + (size_t)r * 256;

        f32x4 val;
        if (k == 0) {
            val = (f32x4){colS[0][rp], colS[1][rp], colS[2][rp], colS[3][rp]};
        } else if (k == 64) {
            val = (f32x4){colS[5][rp], colS[6][rp], colS[7][rp], colS[8][rp]};
        } else {
            f32x2 a = __builtin_nontemporal_load((const f32x2*)(xrow + 4 * k - 2));
            f32x2 c = __builtin_nontemporal_load((const f32x2*)(xrow + 4 * k));
            val = (f32x4){a.x, a.y, c.x, c.y};
        }
        __builtin_nontemporal_store(val, (f32x4*)(orow + 4 * k));
    }
}

extern "C" void kernel_launch(void* const* d_in, const int* in_sizes, int n_in,
                              void* d_out, int out_size, void* d_ws, size_t ws_size,
                              hipStream_t stream)
{
    const float* x  = (const float*)d_in[0];
    const float* w1 = (const float*)d_in[1];
    const float* b1 = (const float*)d_in[2];
    const float* w2 = (const float*)d_in[3];
    const float* b2 = (const float*)d_in[4];
    const float* w3 = (const float*)d_in[5];
    const float* b3 = (const float*)d_in[6];
    float* out = (float*)d_out;

    fused_kernel<<<1024, 512, 0, stream>>>(x, w1, b1, w2, b2, w3, b3, out);
}